// Round 5
// baseline (1949.801 us; speedup 1.0000x reference)
//
#include <hip/hip_runtime.h>
#include <hip/hip_bf16.h>

typedef unsigned int u32;
typedef unsigned short u16;
typedef _Float16 f16;
typedef float f32x2 __attribute__((ext_vector_type(2)));
typedef _Float16 f16x2 __attribute__((ext_vector_type(2)));
typedef u32 u32x4 __attribute__((ext_vector_type(4)));

#define LN_EPS 1e-5f
#define T_STEPS 30
#define NAG 4096
#define GA 16        // agents per k_gru block

__device__ __forceinline__ float bf2f(u16 v){
    union { u32 u; float f; } c; c.u = ((u32)v) << 16; return c.f;
}
__device__ __forceinline__ u16 f2bf(float f){
    union { float f; u32 u; } c; c.f = f;
    return (u16)((c.u + 0x7FFFu + ((c.u >> 16) & 1u)) >> 16);
}
__device__ __forceinline__ u32 pk_h2(float a, float b){
    f16x2 h; h[0] = (f16)a; h[1] = (f16)b;
    return __builtin_bit_cast(u32, h);
}
__device__ __forceinline__ f32x2 unpk_h2(u32 p){
    f16x2 h = __builtin_bit_cast(f16x2, p);
    f32x2 r; r[0] = (float)h[0]; r[1] = (float)h[1]; return r;
}
// bf16 pair (u32) -> f16 pair (u32)
__device__ __forceinline__ u32 bfp2h2(u32 p){
    union { u32 u; float f; } a, b;
    a.u = p << 16; b.u = p & 0xFFFF0000u;
    return pk_h2(a.f, b.f);
}
// v_dot2_f32_f16: c += a.x*b.x + a.y*b.y
__device__ __forceinline__ float fdot2u(u32 a, u32 b, float c){
    return __builtin_amdgcn_fdot2(__builtin_bit_cast(f16x2, a),
                                  __builtin_bit_cast(f16x2, b), c, false);
}
// dtype probe: fp32 buffers read as u16 have random mantissa halves at even
// positions (~50% decode to |x|>=128); bf16 weight buffers (|w| < 1) never do.
__device__ __forceinline__ int detect_f32(const void* probe){
    const u16* p = (const u16*)probe;
    int bad = 0;
    #pragma unroll
    for (int i = 0; i < 32; i++){
        u32 e = (p[2*i] >> 7) & 0xFF;
        bad += (e >= 0x86) ? 1 : 0;
    }
    return bad > 4;
}
__device__ __forceinline__ float ldin(const void* p, int i, int F){
    float v;
    if (F) v = ((const float*)p)[i];
    else   v = bf2f(((const u16*)p)[i]);
    return v;
}
// load element-pair (2*pairIdx, 2*pairIdx+1) as packed f16 pair
__device__ __forceinline__ u32 ld_pair(const void* p, int pairIdx, int F){
    if (F){ const float* f = (const float*)p; return pk_h2(f[2*pairIdx], f[2*pairIdx+1]); }
    return bfp2h2(((const u32*)p)[pairIdx]);
}
__device__ __forceinline__ void wred64(float& s, float& q){
    #pragma unroll
    for (int m = 1; m < 64; m <<= 1){ s += __shfl_xor(s, m); q += __shfl_xor(q, m); }
}
__device__ __forceinline__ void wred32(float& s, float& q){
    #pragma unroll
    for (int m = 1; m < 32; m <<= 1){ s += __shfl_xor(s, m); q += __shfl_xor(q, m); }
}
__device__ __forceinline__ float lrelu(float x){ return fmaxf(x, 0.1f * x); }
__device__ __forceinline__ float sigm(float x){ return 1.0f / (1.0f + __expf(-x)); }
__device__ __forceinline__ float ftanh(float x){ return 1.0f - 2.0f / (1.0f + __expf(2.0f * x)); }
__device__ __forceinline__ void ln128(float a0, float a1, float& o0, float& o1){
    float s = a0 + a1, q = a0*a0 + a1*a1;
    wred64(s, q);
    float m = s * (1.f/128.f), v = q * (1.f/128.f) - m*m;
    float rs = rsqrtf(fmaxf(v, 0.f) + LN_EPS);
    o0 = (a0 - m) * rs; o1 = (a1 - m) * rs;
}

// ---------------- K1: cond embeddings (both dirs): [N,2] -> 64 -> 128 ----------------
__global__ __launch_bounds__(64) void k_cond(
    const void* __restrict__ cond,
    const void* __restrict__ w1a, const void* __restrict__ b1a,
    const void* __restrict__ w2a, const void* __restrict__ b2a,
    const void* __restrict__ w1b, const void* __restrict__ b1b,
    const void* __restrict__ w2b, const void* __restrict__ b2b,
    const void* __restrict__ probe,
    f16* __restrict__ disp)
{
    __shared__ float x1s[64];
    int F = detect_f32(probe);
    int n = blockIdx.x, dir = blockIdx.y, lane = threadIdx.x;
    const void* w1 = dir ? w1b : w1a; const void* b1 = dir ? b1b : b1a;
    const void* w2 = dir ? w2b : w2a; const void* b2 = dir ? b2b : b2a;
    float c0 = ldin(cond, n*2, F), c1 = ldin(cond, n*2+1, F);
    float y = ldin(w1, lane*2, F) * c0 + ldin(w1, lane*2+1, F) * c1 + ldin(b1, lane, F);
    float s = y, q = y*y; wred64(s, q);
    float m = s * (1.f/64.f), v = q * (1.f/64.f) - m*m;
    float rs = rsqrtf(fmaxf(v, 0.f) + LN_EPS);
    x1s[lane] = lrelu((y - m) * rs);
    __syncthreads();
    float y0 = ldin(b2, lane, F), y1 = ldin(b2, lane+64, F);
    for (int k = 0; k < 64; k++){
        float xv = x1s[k];
        y0 += ldin(w2, lane*64+k, F) * xv;
        y1 += ldin(w2, (lane+64)*64+k, F) * xv;
    }
    float o0, o1; ln128(y0, y1, o0, o1);
    f16* dp = disp + ((size_t)dir * NAG + n) * 128;
    dp[lane] = (f16)lrelu(o0);
    dp[lane+64] = (f16)lrelu(o1);
}

// ---------------- K2: scene embedding: z[T,N,128] -> 32 -> 64 (packed fdot2) ----------
__global__ __launch_bounds__(256) void k_emb(
    const void* __restrict__ z,
    const void* __restrict__ iw1, const void* __restrict__ ib1,
    const void* __restrict__ iw2, const void* __restrict__ ib2,
    const void* __restrict__ probe,
    f16* __restrict__ semb)
{
    __shared__ u32 w1p[64*32];      // [kp<64][e<32]
    __shared__ u32 w2p[16*64];      // [kp<16][e<64]
    __shared__ u32 zp[4][2][64];    // z rows packed, 2 rows per wave pass
    __shared__ u32 x1p[4][2][16];   // layer-1 outs packed
    int F = detect_f32(probe);
    int tid = threadIdx.x;
    for (int i = tid; i < 2048; i += 256){
        int kp = i >> 5, e = i & 31;
        w1p[kp*32+e] = ld_pair(iw1, e*64 + kp, F);      // iw1 [32][128]
    }
    for (int i = tid; i < 1024; i += 256){
        int kp = i >> 6, e = i & 63;
        w2p[kp*64+e] = ld_pair(iw2, e*16 + kp, F);      // iw2 [64][32]
    }
    __syncthreads();
    int w = tid >> 6, lane = tid & 63;
    int rp = lane >> 5, ll = lane & 31;
    float b1v = ldin(ib1, ll, F);
    float b2v = ldin(ib2, lane, F);
    int rowbase = (blockIdx.x * 4 + w) * 8;
    #pragma unroll 1
    for (int pass = 0; pass < 4; pass++){
        int row = rowbase + pass*2 + rp;                // half-wave rp owns this row
        zp[w][rp][ll]    = ld_pair(z, row*64 + ll, F);
        zp[w][rp][ll+32] = ld_pair(z, row*64 + ll + 32, F);
        // L1: out e = ll for row rp
        float y1 = b1v;
        #pragma unroll 8
        for (int kp = 0; kp < 64; kp++)
            y1 = fdot2u(zp[w][rp][kp], w1p[kp*32+ll], y1);
        float s = y1, q = y1*y1; wred32(s, q);
        float m = s*(1.f/32.f), v = q*(1.f/32.f)-m*m, rs = rsqrtf(fmaxf(v,0.f)+LN_EPS);
        float sv = lrelu((y1-m)*rs);
        float e0 = __shfl(sv, (lane & 32) + 2*(lane & 15));
        float e1 = __shfl(sv, (lane & 32) + 2*(lane & 15) + 1);
        if (ll < 16) x1p[w][rp][ll] = pk_h2(e0, e1);
        // L2: both rows, full wave each
        #pragma unroll
        for (int r2 = 0; r2 < 2; r2++){
            float y2 = b2v;
            #pragma unroll
            for (int kp = 0; kp < 16; kp++)
                y2 = fdot2u(x1p[w][r2][kp], w2p[kp*64+lane], y2);
            s = y2; q = y2*y2; wred64(s, q);
            m = s*(1.f/64.f); v = q*(1.f/64.f)-m*m; rs = rsqrtf(fmaxf(v,0.f)+LN_EPS);
            semb[(size_t)(rowbase + pass*2 + r2)*64 + lane] = (f16)lrelu((y2-m)*rs);
        }
    }
}

// ---------------- K3: bidirectional LN-GRU, output-stationary, Whh in VGPRs ----------
// grid (256, 2), 384 thr = 6 waves. Wave w: gate = w>>1 (r,z,n), half = w&1.
// Lane's unit row = gate*128 + half*64 + lane. Whh[row][:] lives in 64 VGPRs
// (f16 pairs); Wih in LDS [kp][row]. h/x in LDS as f16 pairs, read broadcast-b128.
__global__ __launch_bounds__(384, 3) void k_gru(
    const f16* __restrict__ semb, const f16* __restrict__ disp,
    const void* __restrict__ wihA, const void* __restrict__ whhA,
    const void* __restrict__ bihA, const void* __restrict__ bhhA,
    const void* __restrict__ wihB, const void* __restrict__ whhB,
    const void* __restrict__ bihB, const void* __restrict__ bhhB,
    const void* __restrict__ probe,
    f16* __restrict__ hencF, f16* __restrict__ hencB)
{
    __shared__ u32 WihT[32*384];                   // [kp][row] f16 pairs (48 KB)
    __shared__ __align__(16) u32 hbuf[GA][64];     // h pairs per agent
    __shared__ __align__(16) u32 xbuf[2][GA][32];  // x pairs, double-buffered
    __shared__ float rzbuf[2][GA][128];            // r,z per agent per unit (16 KB)
    __shared__ float redS[6][GA], redQ[6][GA];
    int F = detect_f32(probe);
    int tid = threadIdx.x, dir = blockIdx.y;
    int w = tid >> 6, lane = tid & 63;
    int gate = w >> 1, half = w & 1;
    int row = gate*128 + half*64 + lane;           // unit row in [0,384)
    const void* wih = dir ? wihB : wihA;  const void* whh = dir ? whhB : whhA;
    const void* bih = dir ? bihB : bihA;  const void* bhh = dir ? bhhB : bhhA;
    f16* henc = dir ? hencB : hencF;

    // Whh row -> 64 VGPRs. Dtype branch HOISTED; fully unrolled, constant indices.
    u32 wh[64];
    float bh, bi;
    if (F){
        const float* W = (const float*)whh + (size_t)row*128;
        #pragma unroll
        for (int j = 0; j < 64; j++) wh[j] = pk_h2(W[2*j], W[2*j+1]);
        bh = ((const float*)bhh)[row]; bi = ((const float*)bih)[row];
    } else {
        const u32* W = (const u32*)whh + (size_t)row*64;
        #pragma unroll
        for (int j = 0; j < 64; j++) wh[j] = bfp2h2(W[j]);
        bh = bf2f(((const u16*)bhh)[row]); bi = bf2f(((const u16*)bih)[row]);
    }
    // Wih -> LDS [kp][row]
    for (int i = tid; i < 12288; i += 384){
        int u = i >> 5, kp = i & 31;
        WihT[kp*384 + u] = ld_pair(wih, u*32 + kp, F);
    }
    // h0 and x(t0) staging
    int nb = blockIdx.x * GA;
    const u32* dispu = (const u32*)disp;
    for (int i = tid; i < GA*64; i += 384){
        int a = i >> 6, k = i & 63;
        hbuf[a][k] = dispu[((size_t)dir*NAG + nb + a)*64 + k];
    }
    const u32* sembu = (const u32*)semb;
    int tx0 = dir ? (T_STEPS-1) : 0;
    for (int i = tid; i < GA*32; i += 384){
        int a = i >> 5, k = i & 31;
        xbuf[0][a][k] = sembu[((size_t)tx0*NAG + nb + a)*32 + k];
    }
    __syncthreads();

    #pragma unroll 1
    for (int t = 0; t < T_STEPS; t++){
        int tx = dir ? (T_STEPS-1-t) : t;
        int cur = t & 1, nxt = cur ^ 1;
        float acc[GA], axi[GA];
        #pragma unroll
        for (int a = 0; a < GA; a++){ acc[a] = bh; axi[a] = bi; }
        // hh dots: register weights, broadcast h reads
        #pragma unroll
        for (int k4 = 0; k4 < 16; k4++){
            #pragma unroll
            for (int a = 0; a < GA; a++){
                u32x4 h4 = *(const u32x4*)&hbuf[a][k4*4];
                float c = acc[a];
                c = fdot2u(h4.x, wh[4*k4+0], c);
                c = fdot2u(h4.y, wh[4*k4+1], c);
                c = fdot2u(h4.z, wh[4*k4+2], c);
                c = fdot2u(h4.w, wh[4*k4+3], c);
                acc[a] = c;
            }
        }
        // ih dots: LDS weights (32 lane-varying reads), broadcast x reads
        #pragma unroll
        for (int k4 = 0; k4 < 8; k4++){
            u32 wiv0 = WihT[(k4*4+0)*384 + row];
            u32 wiv1 = WihT[(k4*4+1)*384 + row];
            u32 wiv2 = WihT[(k4*4+2)*384 + row];
            u32 wiv3 = WihT[(k4*4+3)*384 + row];
            #pragma unroll
            for (int a = 0; a < GA; a++){
                u32x4 x4 = *(const u32x4*)&xbuf[cur][a][k4*4];
                float c = axi[a];
                c = fdot2u(x4.x, wiv0, c);
                c = fdot2u(x4.y, wiv1, c);
                c = fdot2u(x4.z, wiv2, c);
                c = fdot2u(x4.w, wiv3, c);
                axi[a] = c;
            }
        }
        // r/z: fold ih into pre-activation; wave-level LN partials
        if (gate < 2){
            #pragma unroll
            for (int a = 0; a < GA; a++){
                float p = acc[a] + axi[a];
                acc[a] = p;
                float s = p, q = p*p; wred64(s, q);
                if (lane == a){ redS[w][a] = s; redQ[w][a] = q; }
            }
        }
        __syncthreads();                               // bar1
        if (gate < 2){
            #pragma unroll
            for (int a = 0; a < GA; a++){
                float s = redS[w][a] + redS[w^1][a];
                float q = redQ[w][a] + redQ[w^1][a];
                float m = s*(1.f/128.f), v = q*(1.f/128.f) - m*m;
                float rs = rsqrtf(fmaxf(v, 0.f) + LN_EPS);
                rzbuf[gate][a][half*64+lane] = sigm((acc[a] - m)*rs);
            }
        } else if (t + 1 < T_STEPS){
            // idle n-waves (128 threads) prefetch next step's x into the other buffer
            int txn = dir ? (T_STEPS-2-t) : (t+1);
            int i0 = (w - 4)*64 + lane;                // [0,128)
            #pragma unroll
            for (int j = 0; j < 4; j++){
                int i = i0 + 128*j;
                int a = i >> 5, k = i & 31;
                xbuf[nxt][a][k] = sembu[((size_t)txn*NAG + nb + a)*32 + k];
            }
        }
        __syncthreads();                               // bar2: rzbuf ready
        if (gate == 2){
            #pragma unroll
            for (int a = 0; a < GA; a++){
                float r = rzbuf[0][a][half*64+lane];
                float p = axi[a] + r*acc[a];
                axi[a] = p;
                float s = p, q = p*p; wred64(s, q);
                if (lane == a){ redS[w][a] = s; redQ[w][a] = q; }
            }
        }
        __syncthreads();                               // bar3
        if (gate == 2){
            #pragma unroll
            for (int a = 0; a < GA; a++){
                float s = redS[w][a] + redS[w^1][a];   // 4 <-> 5
                float q = redQ[w][a] + redQ[w^1][a];
                float m = s*(1.f/128.f), v = q*(1.f/128.f) - m*m;
                float rs = rsqrtf(fmaxf(v, 0.f) + LN_EPS);
                float n = ftanh((axi[a] - m)*rs);
                float z = rzbuf[1][a][half*64+lane];
                u32 hp2 = hbuf[a][half*32 + (lane >> 1)];
                f16x2 hph = __builtin_bit_cast(f16x2, hp2);
                float hp = (float)((lane & 1) ? hph[1] : hph[0]);
                float hn = (1.f - z)*n + z*hp;
                henc[((size_t)tx*NAG + nb + a)*128 + half*64 + lane] = (f16)hn;
                float e0 = __shfl(hn, 2*(lane & 31));
                float e1 = __shfl(hn, 2*(lane & 31) + 1);
                if (lane < 32) hbuf[a][half*32 + lane] = pk_h2(e0, e1);
            }
        }
        __syncthreads();                               // bar4: hbuf/xbuf ready
    }
}

// ---------------- K4: fused post-GRU: seq -> pairwise(factored) -> out head ----------------
// wave = one (t,scene). Pairwise Linear factored: W(s_i-s_j)+b = u_i - u_j + b.
__global__ __launch_bounds__(256) void k_post(
    const f16* __restrict__ hf, const f16* __restrict__ hb,
    const void* __restrict__ sw, const void* __restrict__ sb,
    const void* __restrict__ mw, const void* __restrict__ mb,
    const void* __restrict__ ow1, const void* __restrict__ ob1,
    const void* __restrict__ ow2, const void* __restrict__ ob2,
    const void* __restrict__ probe,
    void* __restrict__ outp)
{
    __shared__ u32 swp[64*64];     // [kp][unit]
    __shared__ u32 mwp[32*64];     // [kp][unit]
    __shared__ u32 w1p[64*32];     // [kp][e<32]
    __shared__ u32 xr[4][8][64];   // x=(hf+hb)/2 as f16 pairs
    __shared__ u32 fr[4][8][64];   // full=[seq|ave] pairs
    int F = detect_f32(probe);
    int tid = threadIdx.x;
    for (int i = tid; i < 4096; i += 256){
        int u = i & 63, kp = i >> 6;
        swp[kp*64+u] = ld_pair(sw, u*64 + kp, F);      // sw [64][128]
    }
    for (int i = tid; i < 2048; i += 256){
        int u = i & 63, kp = i >> 6;   // kp < 32
        mwp[kp*64+u] = ld_pair(mw, u*32 + kp, F);      // mw [64][64]
    }
    for (int i = tid; i < 2048; i += 256){
        int e = i & 31, kp = i >> 5;   // kp < 64
        w1p[kp*32+e] = ld_pair(ow1, e*64 + kp, F);     // ow1 [32][128]
    }
    int w = tid >> 6, lane = tid & 63;
    int unit = blockIdx.x*4 + w;        // t*512 + scene
    int t = unit >> 9, sc = unit & 511;
    int base = sc * 8;
    size_t rowbase = (size_t)t*NAG + base;
    const u32* hfu = (const u32*)hf;
    const u32* hbu = (const u32*)hb;
    #pragma unroll
    for (int r = 0; r < 8; r++){
        f32x2 a = unpk_h2(hfu[(rowbase + r)*64 + lane]);
        f32x2 b = unpk_h2(hbu[(rowbase + r)*64 + lane]);
        xr[w][r][lane] = pk_h2(0.5f*(a[0]+b[0]), 0.5f*(a[1]+b[1]));
    }
    __syncthreads();

    float bs = ldin(sb, lane, F);
    float y[8];
    #pragma unroll
    for (int r = 0; r < 8; r++) y[r] = bs;
    for (int kp = 0; kp < 64; kp++){
        u32 wv = swp[kp*64 + lane];
        #pragma unroll
        for (int r = 0; r < 8; r++) y[r] = fdot2u(xr[w][r][kp], wv, y[r]);
    }
    #pragma unroll
    for (int r = 0; r < 8; r++){
        float s = y[r], q = y[r]*y[r]; wred64(s, q);
        float m = s*(1.f/64.f), v = q*(1.f/64.f) - m*m;
        float rs = rsqrtf(fmaxf(v, 0.f) + LN_EPS);
        float sv = lrelu((y[r] - m)*rs);
        float e0 = __shfl(sv, 2*(lane & 31)), e1 = __shfl(sv, 2*(lane & 31) + 1);
        if (lane < 32) fr[w][r][lane] = pk_h2(e0, e1);
    }
    float uu[8];
    #pragma unroll
    for (int r = 0; r < 8; r++) uu[r] = 0.f;
    for (int kp = 0; kp < 32; kp++){
        u32 wv = mwp[kp*64 + lane];
        #pragma unroll
        for (int r = 0; r < 8; r++) uu[r] = fdot2u(fr[w][r][kp], wv, uu[r]);
    }
    float bm = ldin(mb, lane, F);
    #pragma unroll
    for (int i = 0; i < 8; i++){
        float acc = 0.f;
        #pragma unroll
        for (int j = 0; j < 8; j++){
            if (j == i) continue;
            float p = uu[i] - uu[j] + bm;
            float s = p, q = p*p; wred64(s, q);
            float m = s*(1.f/64.f), v = q*(1.f/64.f) - m*m;
            float rs = rsqrtf(fmaxf(v, 0.f) + LN_EPS);
            acc += lrelu((p - m)*rs);
        }
        float av = acc * (1.f/7.f);
        float e0 = __shfl(av, 2*(lane & 31)), e1 = __shfl(av, 2*(lane & 31) + 1);
        if (lane < 32) fr[w][i][32 + lane] = pk_h2(e0, e1);
    }
    int ll = lane & 31;
    float b1v = ldin(ob1, ll, F);
    float o20 = ldin(ow2, ll, F);
    float o21 = ldin(ow2, 32 + ll, F);
    float bo0 = ldin(ob2, 0, F), bo1 = ldin(ob2, 1, F);
    #pragma unroll
    for (int rp = 0; rp < 4; rp++){
        int r = rp*2 + (lane >> 5);
        float h = b1v;
        for (int kp = 0; kp < 64; kp++)
            h = fdot2u(fr[w][r][kp], w1p[kp*32 + ll], h);
        float s = h, q = h*h; wred32(s, q);
        float m = s*(1.f/32.f), v = q*(1.f/32.f) - m*m;
        float rs = rsqrtf(fmaxf(v, 0.f) + LN_EPS);
        float hv = lrelu((h - m)*rs);
        float p0 = hv*o20, p1 = hv*o21;
        wred32(p0, p1);
        if (ll == 0){
            int n = base + r;
            float v0 = ftanh(p0 + bo0), v1 = ftanh(p1 + bo1);
            size_t i0 = (size_t)(n*2)*T_STEPS + t, i1 = (size_t)(n*2+1)*T_STEPS + t;
            if (F){ ((float*)outp)[i0] = v0; ((float*)outp)[i1] = v1; }
            else  { ((u16*)outp)[i0] = f2bf(v0); ((u16*)outp)[i1] = f2bf(v1); }
        }
    }
}

extern "C" void kernel_launch(void* const* d_in, const int* in_sizes, int n_in,
                              void* d_out, int out_size, void* d_ws, size_t ws_size,
                              hipStream_t stream)
{
    const void* cond = d_in[0];
    const void* z    = d_in[1];
    const void* cw1  = d_in[2];
    const void* cb1  = d_in[3];
    const void* cw2  = d_in[4];
    const void* cb2  = d_in[5];
    const void* cbw1 = d_in[6];
    const void* cbb1 = d_in[7];
    const void* cbw2 = d_in[8];
    const void* cbb2 = d_in[9];
    const void* iw1  = d_in[10];
    const void* ib1  = d_in[11];
    const void* iw2  = d_in[12];
    const void* ib2  = d_in[13];
    const void* wih  = d_in[14];
    const void* whh  = d_in[15];
    const void* bih  = d_in[16];
    const void* bhh  = d_in[17];
    const void* wihb = d_in[18];
    const void* whhb = d_in[19];
    const void* bihb = d_in[20];
    const void* bhhb = d_in[21];
    const void* sw   = d_in[22];
    const void* sb   = d_in[23];
    const void* mw   = d_in[24];
    const void* mb   = d_in[25];
    const void* ow1  = d_in[26];
    const void* ob1  = d_in[27];
    const void* ow2  = d_in[28];
    const void* ob2  = d_in[29];
    const void* probe = whh;   // dtype-detection probe buffer

    char* ws = (char*)d_ws;
    size_t off = 0;
    f16* disp  = (f16*)(ws + off); off += (size_t)2*NAG*128*2;          //  2 MB
    f16* semb  = (f16*)(ws + off); off += (size_t)T_STEPS*NAG*64*2;     // 15.7 MB
    f16* hencF = (f16*)(ws + off); off += (size_t)T_STEPS*NAG*128*2;    // 31.5 MB
    f16* hencB = (f16*)(ws + off); off += (size_t)T_STEPS*NAG*128*2;    // 31.5 MB

    k_cond<<<dim3(NAG,2), 64, 0, stream>>>(cond, cw1,cb1,cw2,cb2, cbw1,cbb1,cbw2,cbb2, probe, disp);
    k_emb<<<3840, 256, 0, stream>>>(z, iw1,ib1,iw2,ib2, probe, semb);
    k_gru<<<dim3(NAG/GA,2), 384, 0, stream>>>(semb, disp, wih,whh,bih,bhh, wihb,whhb,bihb,bhhb, probe, hencF, hencB);
    k_post<<<3840, 256, 0, stream>>>(hencF, hencB, sw,sb, mw,mb, ow1,ob1,ow2,ob2, probe, d_out);
}

// Round 6
// 1208.930 us; speedup vs baseline: 1.6128x; 1.6128x over previous
//
#include <hip/hip_runtime.h>
#include <hip/hip_bf16.h>

typedef unsigned int u32;
typedef unsigned short u16;
typedef _Float16 f16;
typedef float f32x2 __attribute__((ext_vector_type(2)));
typedef _Float16 f16x2 __attribute__((ext_vector_type(2)));
typedef u32 u32x4 __attribute__((ext_vector_type(4)));

#define LN_EPS 1e-5f
#define T_STEPS 30
#define NAG 4096

__device__ __forceinline__ float bf2f(u16 v){
    union { u32 u; float f; } c; c.u = ((u32)v) << 16; return c.f;
}
__device__ __forceinline__ u16 f2bf(float f){
    union { float f; u32 u; } c; c.f = f;
    return (u16)((c.u + 0x7FFFu + ((c.u >> 16) & 1u)) >> 16);
}
__device__ __forceinline__ u32 pk_h2(float a, float b){
    f16x2 h; h[0] = (f16)a; h[1] = (f16)b;
    return __builtin_bit_cast(u32, h);
}
__device__ __forceinline__ f32x2 unpk_h2(u32 p){
    f16x2 h = __builtin_bit_cast(f16x2, p);
    f32x2 r; r[0] = (float)h[0]; r[1] = (float)h[1]; return r;
}
// bf16 pair (u32) -> f16 pair (u32)
__device__ __forceinline__ u32 bfp2h2(u32 p){
    union { u32 u; float f; } a, b;
    a.u = p << 16; b.u = p & 0xFFFF0000u;
    return pk_h2(a.f, b.f);
}
// v_dot2_f32_f16: c += a.x*b.x + a.y*b.y
__device__ __forceinline__ float fdot2u(u32 a, u32 b, float c){
    return __builtin_amdgcn_fdot2(__builtin_bit_cast(f16x2, a),
                                  __builtin_bit_cast(f16x2, b), c, false);
}
// dtype probe: fp32 buffers read as u16 have random mantissa halves at even
// positions (~50% decode to |x|>=128); bf16 weight buffers (|w| < 1) never do.
__device__ __forceinline__ int detect_f32(const void* probe){
    const u16* p = (const u16*)probe;
    int bad = 0;
    #pragma unroll
    for (int i = 0; i < 32; i++){
        u32 e = (p[2*i] >> 7) & 0xFF;
        bad += (e >= 0x86) ? 1 : 0;
    }
    return bad > 4;
}
__device__ __forceinline__ float ldin(const void* p, int i, int F){
    float v;
    if (F) v = ((const float*)p)[i];
    else   v = bf2f(((const u16*)p)[i]);
    return v;
}
// load element-pair (2*pairIdx, 2*pairIdx+1) as packed f16 pair
__device__ __forceinline__ u32 ld_pair(const void* p, int pairIdx, int F){
    if (F){ const float* f = (const float*)p; return pk_h2(f[2*pairIdx], f[2*pairIdx+1]); }
    return bfp2h2(((const u32*)p)[pairIdx]);
}
__device__ __forceinline__ void wred64(float& s, float& q){
    #pragma unroll
    for (int m = 1; m < 64; m <<= 1){ s += __shfl_xor(s, m); q += __shfl_xor(q, m); }
}
__device__ __forceinline__ void wred32(float& s, float& q){
    #pragma unroll
    for (int m = 1; m < 32; m <<= 1){ s += __shfl_xor(s, m); q += __shfl_xor(q, m); }
}
__device__ __forceinline__ float lrelu(float x){ return fmaxf(x, 0.1f * x); }
__device__ __forceinline__ float sigm(float x){ return 1.0f / (1.0f + __expf(-x)); }
__device__ __forceinline__ float ftanh(float x){ return 1.0f - 2.0f / (1.0f + __expf(2.0f * x)); }
__device__ __forceinline__ void ln128(float a0, float a1, float& o0, float& o1){
    float s = a0 + a1, q = a0*a0 + a1*a1;
    wred64(s, q);
    float m = s * (1.f/128.f), v = q * (1.f/128.f) - m*m;
    float rs = rsqrtf(fmaxf(v, 0.f) + LN_EPS);
    o0 = (a0 - m) * rs; o1 = (a1 - m) * rs;
}

// ---------------- K1: cond embeddings (both dirs): [N,2] -> 64 -> 128 ----------------
__global__ __launch_bounds__(64) void k_cond(
    const void* __restrict__ cond,
    const void* __restrict__ w1a, const void* __restrict__ b1a,
    const void* __restrict__ w2a, const void* __restrict__ b2a,
    const void* __restrict__ w1b, const void* __restrict__ b1b,
    const void* __restrict__ w2b, const void* __restrict__ b2b,
    const void* __restrict__ probe,
    f16* __restrict__ disp)
{
    __shared__ float x1s[64];
    int F = detect_f32(probe);
    int n = blockIdx.x, dir = blockIdx.y, lane = threadIdx.x;
    const void* w1 = dir ? w1b : w1a; const void* b1 = dir ? b1b : b1a;
    const void* w2 = dir ? w2b : w2a; const void* b2 = dir ? b2b : b2a;
    float c0 = ldin(cond, n*2, F), c1 = ldin(cond, n*2+1, F);
    float y = ldin(w1, lane*2, F) * c0 + ldin(w1, lane*2+1, F) * c1 + ldin(b1, lane, F);
    float s = y, q = y*y; wred64(s, q);
    float m = s * (1.f/64.f), v = q * (1.f/64.f) - m*m;
    float rs = rsqrtf(fmaxf(v, 0.f) + LN_EPS);
    x1s[lane] = lrelu((y - m) * rs);
    __syncthreads();
    float y0 = ldin(b2, lane, F), y1 = ldin(b2, lane+64, F);
    for (int k = 0; k < 64; k++){
        float xv = x1s[k];
        y0 += ldin(w2, lane*64+k, F) * xv;
        y1 += ldin(w2, (lane+64)*64+k, F) * xv;
    }
    float o0, o1; ln128(y0, y1, o0, o1);
    f16* dp = disp + ((size_t)dir * NAG + n) * 128;
    dp[lane] = (f16)lrelu(o0);
    dp[lane+64] = (f16)lrelu(o1);
}

// ---------------- K2: scene embedding: z[T,N,128] -> 32 -> 64 (packed fdot2) ----------
__global__ __launch_bounds__(256) void k_emb(
    const void* __restrict__ z,
    const void* __restrict__ iw1, const void* __restrict__ ib1,
    const void* __restrict__ iw2, const void* __restrict__ ib2,
    const void* __restrict__ probe,
    f16* __restrict__ semb)
{
    __shared__ u32 w1p[64*32];      // [kp<64][e<32]
    __shared__ u32 w2p[16*64];      // [kp<16][e<64]
    __shared__ u32 zp[4][2][64];    // z rows packed, 2 rows per wave pass
    __shared__ u32 x1p[4][2][16];   // layer-1 outs packed
    int F = detect_f32(probe);
    int tid = threadIdx.x;
    for (int i = tid; i < 2048; i += 256){
        int kp = i >> 5, e = i & 31;
        w1p[kp*32+e] = ld_pair(iw1, e*64 + kp, F);      // iw1 [32][128]
    }
    for (int i = tid; i < 1024; i += 256){
        int kp = i >> 6, e = i & 63;
        w2p[kp*64+e] = ld_pair(iw2, e*16 + kp, F);      // iw2 [64][32]
    }
    __syncthreads();
    int w = tid >> 6, lane = tid & 63;
    int rp = lane >> 5, ll = lane & 31;
    float b1v = ldin(ib1, ll, F);
    float b2v = ldin(ib2, lane, F);
    int rowbase = (blockIdx.x * 4 + w) * 8;
    #pragma unroll 1
    for (int pass = 0; pass < 4; pass++){
        int row = rowbase + pass*2 + rp;                // half-wave rp owns this row
        zp[w][rp][ll]    = ld_pair(z, row*64 + ll, F);
        zp[w][rp][ll+32] = ld_pair(z, row*64 + ll + 32, F);
        // L1: out e = ll for row rp
        float y1 = b1v;
        #pragma unroll 8
        for (int kp = 0; kp < 64; kp++)
            y1 = fdot2u(zp[w][rp][kp], w1p[kp*32+ll], y1);
        float s = y1, q = y1*y1; wred32(s, q);
        float m = s*(1.f/32.f), v = q*(1.f/32.f)-m*m, rs = rsqrtf(fmaxf(v,0.f)+LN_EPS);
        float sv = lrelu((y1-m)*rs);
        float e0 = __shfl(sv, (lane & 32) + 2*(lane & 15));
        float e1 = __shfl(sv, (lane & 32) + 2*(lane & 15) + 1);
        if (ll < 16) x1p[w][rp][ll] = pk_h2(e0, e1);
        // L2: both rows, full wave each
        #pragma unroll
        for (int r2 = 0; r2 < 2; r2++){
            float y2 = b2v;
            #pragma unroll
            for (int kp = 0; kp < 16; kp++)
                y2 = fdot2u(x1p[w][r2][kp], w2p[kp*64+lane], y2);
            s = y2; q = y2*y2; wred64(s, q);
            m = s*(1.f/64.f); v = q*(1.f/64.f)-m*m; rs = rsqrtf(fmaxf(v,0.f)+LN_EPS);
            semb[(size_t)(rowbase + pass*2 + r2)*64 + lane] = (f16)lrelu((y2-m)*rs);
        }
    }
}

// ---------------- K2b: xg = semb @ Wih^T + bih, both dirs, all T (no recurrence) -----
// block 256 = 4 waves x 8 rows; blockIdx.y = dir. Wih in LDS, XOR-swizzled b128.
__global__ __launch_bounds__(256) void k_xg(
    const f16* __restrict__ semb,
    const void* __restrict__ wihA, const void* __restrict__ bihA,
    const void* __restrict__ wihB, const void* __restrict__ bihB,
    const void* __restrict__ probe,
    f16* __restrict__ xg)
{
    __shared__ __align__(16) u32 WihS[384*32];   // swizzled: [u][4*((kp/4)^(u&7)) + kp%4]
    __shared__ __align__(16) u32 xs[4][8][32];
    int F = detect_f32(probe);
    int tid = threadIdx.x, dir = blockIdx.y;
    const void* wih = dir ? wihB : wihA;
    const void* bih = dir ? bihB : bihA;
    for (int i = tid; i < 12288; i += 256){
        int u = i >> 5, kp = i & 31;
        WihS[u*32 + 4*((kp>>2) ^ (u & 7)) + (kp & 3)] = ld_pair(wih, u*32 + kp, F);
    }
    __syncthreads();
    int w = tid >> 6, lane = tid & 63;
    float B[6];
    #pragma unroll
    for (int g = 0; g < 6; g++) B[g] = ldin(bih, g*64 + lane, F);
    int rowbase = blockIdx.x*32 + w*8;           // rows in [0, 122880)
    const u32* sembu = (const u32*)semb;
    for (int i = lane; i < 256; i += 64){
        int r = i >> 5, k = i & 31;
        xs[w][r][k] = sembu[(size_t)(rowbase + r)*32 + k];
    }
    float acc[6][8];
    #pragma unroll
    for (int g = 0; g < 6; g++)
        #pragma unroll
        for (int r = 0; r < 8; r++) acc[g][r] = B[g];
    #pragma unroll
    for (int j4 = 0; j4 < 8; j4++){
        u32x4 Wg[6];
        #pragma unroll
        for (int g = 0; g < 6; g++)
            Wg[g] = *(const u32x4*)&WihS[(g*64 + lane)*32 + 4*(j4 ^ (lane & 7))];
        #pragma unroll
        for (int r = 0; r < 8; r++){
            u32x4 x4 = *(const u32x4*)&xs[w][r][j4*4];
            #pragma unroll
            for (int c = 0; c < 4; c++){
                #pragma unroll
                for (int g = 0; g < 6; g++)
                    acc[g][r] = fdot2u(x4[c], Wg[g][c], acc[g][r]);
            }
        }
    }
    #pragma unroll
    for (int r = 0; r < 8; r++){
        f16* op = xg + ((size_t)dir*T_STEPS*NAG + rowbase + r)*384;
        #pragma unroll
        for (int g = 0; g < 6; g++) op[g*64 + lane] = (f16)acc[g][r];
    }
}

// ---------------- K3 (fast): bidirectional LN-GRU, hh-only, swizzled-b128 weights ----
// grid (128, 2), 512 thr = 8 waves x 4 agents. Whh in LDS unit-major, 16B blocks
// XOR-swizzled so the 6 unit-streams per lane are conflict-free ds_read_b128.
// xg pre-activations streamed from global per step. No barrier in the t-loop.
__global__ __launch_bounds__(512) void k_gru_fast(
    const f16* __restrict__ xg, const f16* __restrict__ disp,
    const void* __restrict__ whhA, const void* __restrict__ bhhA,
    const void* __restrict__ whhB, const void* __restrict__ bhhB,
    const void* __restrict__ probe,
    f16* __restrict__ hencF, f16* __restrict__ hencB)
{
    __shared__ __align__(16) u32 WhhS[384*64];   // 96 KB swizzled
    __shared__ __align__(16) u32 hbuf[32][64];   // f16 pairs of h per agent
    int F = detect_f32(probe);
    int tid = threadIdx.x, dir = blockIdx.y;
    const void* whh = dir ? whhB : whhA;
    const void* bhh = dir ? bhhB : bhhA;
    f16* henc = dir ? hencB : hencF;
    for (int i = tid; i < 24576; i += 512){
        int u = i >> 6, kp = i & 63;
        WhhS[u*64 + 4*((kp>>2) ^ (u & 15)) + (kp & 3)] = ld_pair(whh, u*64 + kp, F);
    }
    __syncthreads();   // the ONLY block-wide barrier

    int w = tid >> 6, lane = tid & 63;
    int nb = blockIdx.x * 32 + w * 4;   // first agent of this wave
    // bhh biases per lane-unit
    float Bh[6];
    #pragma unroll
    for (int g = 0; g < 6; g++) Bh[g] = ldin(bhh, g*64 + lane, F);
    float hreg[4][2];
    #pragma unroll
    for (int a = 0; a < 4; a++){
        const f16* dp = disp + ((size_t)dir*NAG + nb + a)*128;
        hreg[a][0] = (float)dp[lane]; hreg[a][1] = (float)dp[lane+64];
        int s0 = (2*lane) & 63, s1 = (2*lane+1) & 63;
        float e0 = __shfl(hreg[a][0], s0), o0 = __shfl(hreg[a][1], s0);
        float e1 = __shfl(hreg[a][0], s1), o1 = __shfl(hreg[a][1], s1);
        hbuf[w*4+a][lane] = pk_h2((lane<32)?e0:o0, (lane<32)?e1:o1);
    }

    #pragma unroll 1
    for (int t = 0; t < T_STEPS; t++){
        int tx = dir ? (T_STEPS-1-t) : t;
        // xg loads issued early (used only in epilogue -> latency hidden by hh dots)
        const f16* xgp = xg + ((size_t)dir*T_STEPS*NAG + (size_t)tx*NAG + nb)*384;
        float xr0[4], xr1[4], xz0[4], xz1[4], xn0[4], xn1[4];
        #pragma unroll
        for (int a = 0; a < 4; a++){
            const f16* xa = xgp + a*384;
            xr0[a] = (float)xa[lane];       xr1[a] = (float)xa[64+lane];
            xz0[a] = (float)xa[128+lane];   xz1[a] = (float)xa[192+lane];
            xn0[a] = (float)xa[256+lane];   xn1[a] = (float)xa[320+lane];
        }
        float A_r0[4], A_r1[4], A_z0[4], A_z1[4], A_h0[4], A_h1[4];
        #pragma unroll
        for (int a = 0; a < 4; a++){
            A_r0[a] = Bh[0]; A_r1[a] = Bh[1];
            A_z0[a] = Bh[2]; A_z1[a] = Bh[3];
            A_h0[a] = Bh[4]; A_h1[a] = Bh[5];
        }
        // hh dots: 6 swizzled b128 weight streams + 4 broadcast b128 h reads per k4
        #pragma unroll 2
        for (int k4 = 0; k4 < 16; k4++){
            int wb = 4*(k4 ^ (lane & 15));
            u32x4 Wr0 = *(const u32x4*)&WhhS[(      lane)*64 + wb];
            u32x4 Wr1 = *(const u32x4*)&WhhS[( 64 + lane)*64 + wb];
            u32x4 Wz0 = *(const u32x4*)&WhhS[(128 + lane)*64 + wb];
            u32x4 Wz1 = *(const u32x4*)&WhhS[(192 + lane)*64 + wb];
            u32x4 Wn0 = *(const u32x4*)&WhhS[(256 + lane)*64 + wb];
            u32x4 Wn1 = *(const u32x4*)&WhhS[(320 + lane)*64 + wb];
            u32x4 h4[4];
            #pragma unroll
            for (int a = 0; a < 4; a++) h4[a] = *(const u32x4*)&hbuf[w*4+a][k4*4];
            #pragma unroll
            for (int c = 0; c < 4; c++){
                #pragma unroll
                for (int a = 0; a < 4; a++){
                    u32 hh = h4[a][c];
                    A_r0[a] = fdot2u(hh, Wr0[c], A_r0[a]);
                    A_r1[a] = fdot2u(hh, Wr1[c], A_r1[a]);
                    A_z0[a] = fdot2u(hh, Wz0[c], A_z0[a]);
                    A_z1[a] = fdot2u(hh, Wz1[c], A_z1[a]);
                    A_h0[a] = fdot2u(hh, Wn0[c], A_h0[a]);
                    A_h1[a] = fdot2u(hh, Wn1[c], A_h1[a]);
                }
            }
        }
        // epilogue per agent: pre-act = xg + hh(+bhh); LN -> gates -> h update
        #pragma unroll
        for (int a = 0; a < 4; a++){
            float g0, g1;
            ln128(A_r0[a] + xr0[a], A_r1[a] + xr1[a], g0, g1);
            float r0 = sigm(g0), r1 = sigm(g1);
            ln128(A_z0[a] + xz0[a], A_z1[a] + xz1[a], g0, g1);
            float z0 = sigm(g0), z1 = sigm(g1);
            float p0 = xn0[a] + r0*A_h0[a], p1 = xn1[a] + r1*A_h1[a];
            ln128(p0, p1, g0, g1);
            float n0 = ftanh(g0), n1 = ftanh(g1);
            float hn0 = (1.f - z0)*n0 + z0*hreg[a][0];
            float hn1 = (1.f - z1)*n1 + z1*hreg[a][1];
            hreg[a][0] = hn0; hreg[a][1] = hn1;
            f16* hp = henc + ((size_t)tx*NAG + nb + a)*128;
            hp[lane] = (f16)hn0; hp[lane+64] = (f16)hn1;
            int sl0 = (2*lane) & 63, sl1 = (2*lane+1) & 63;
            float e0 = __shfl(hn0, sl0), o0 = __shfl(hn1, sl0);
            float e1 = __shfl(hn0, sl1), o1 = __shfl(hn1, sl1);
            hbuf[w*4+a][lane] = pk_h2((lane<32)?e0:o0, (lane<32)?e1:o1);
        }
        // no barrier: each wave only touches its own hbuf rows
    }
}

// ---------------- K3 (fallback, R4-proven): full GRU with ih in-loop ----------------
__global__ __launch_bounds__(512) void k_gru_fb(
    const f16* __restrict__ semb, const f16* __restrict__ disp,
    const void* __restrict__ wihA, const void* __restrict__ whhA,
    const void* __restrict__ bihA, const void* __restrict__ bhhA,
    const void* __restrict__ wihB, const void* __restrict__ whhB,
    const void* __restrict__ bihB, const void* __restrict__ bhhB,
    const void* __restrict__ probe,
    f16* __restrict__ hencF, f16* __restrict__ hencB)
{
    __shared__ u32 WhhT[64*384];
    __shared__ u32 WihT[32*384];
    __shared__ float brz[256];
    __shared__ float bin[128];
    __shared__ float bhn[128];
    __shared__ __align__(16) u32 hbuf[32][64];
    __shared__ __align__(16) u32 xbuf[32][32];
    int F = detect_f32(probe);
    int tid = threadIdx.x, dir = blockIdx.y;
    const void* wih = dir ? wihB : wihA;  const void* whh = dir ? whhB : whhA;
    const void* bih = dir ? bihB : bihA;  const void* bhh = dir ? bhhB : bhhA;
    f16* henc = dir ? hencB : hencF;
    for (int i = tid; i < 24576; i += 512){
        int u = i >> 6, k = i & 63;
        WhhT[k*384 + u] = ld_pair(whh, u*64 + k, F);
    }
    for (int i = tid; i < 12288; i += 512){
        int u = i >> 5, k = i & 31;
        WihT[k*384 + u] = ld_pair(wih, u*32 + k, F);
    }
    if (tid < 256) brz[tid] = ldin(bih, tid, F) + ldin(bhh, tid, F);
    else if (tid < 384){ bin[tid-256] = ldin(bih, tid, F); bhn[tid-256] = ldin(bhh, tid, F); }
    __syncthreads();
    int w = tid >> 6, lane = tid & 63;
    int nb = blockIdx.x * 32 + w * 4;
    const u32* sembu = (const u32*)semb;
    int tx0 = dir ? (T_STEPS-1) : 0;
    float hreg[4][2];
    #pragma unroll
    for (int a = 0; a < 4; a++){
        const f16* dp = disp + ((size_t)dir*NAG + nb + a)*128;
        hreg[a][0] = (float)dp[lane]; hreg[a][1] = (float)dp[lane+64];
        int s0 = (2*lane) & 63, s1 = (2*lane+1) & 63;
        float e0 = __shfl(hreg[a][0], s0), o0 = __shfl(hreg[a][1], s0);
        float e1 = __shfl(hreg[a][0], s1), o1 = __shfl(hreg[a][1], s1);
        hbuf[w*4+a][lane] = pk_h2((lane<32)?e0:o0, (lane<32)?e1:o1);
        if (lane < 32) xbuf[w*4+a][lane] = sembu[((size_t)tx0*NAG + nb + a)*32 + lane];
    }
    float B_r0 = brz[lane],     B_r1 = brz[64+lane];
    float B_z0 = brz[128+lane], B_z1 = brz[192+lane];
    float B_i0 = bin[lane],     B_i1 = bin[64+lane];
    float B_h0 = bhn[lane],     B_h1 = bhn[64+lane];
    #pragma unroll 1
    for (int t = 0; t < T_STEPS; t++){
        int tx = dir ? (T_STEPS-1-t) : t;
        float A_r0[4], A_r1[4], A_z0[4], A_z1[4], A_h0[4], A_h1[4], A_i0[4], A_i1[4];
        #pragma unroll
        for (int a = 0; a < 4; a++){
            A_r0[a] = B_r0; A_r1[a] = B_r1;
            A_z0[a] = B_z0; A_z1[a] = B_z1;
            A_h0[a] = B_h0; A_h1[a] = B_h1;
            A_i0[a] = B_i0; A_i1[a] = B_i1;
        }
        #pragma unroll 2
        for (int k4 = 0; k4 < 16; k4++){
            u32x4 h4[4];
            #pragma unroll
            for (int a = 0; a < 4; a++) h4[a] = *(const u32x4*)&hbuf[w*4+a][k4*4];
            #pragma unroll
            for (int kk = 0; kk < 4; kk++){
                const u32* wrow = &WhhT[(k4*4+kk)*384 + lane];
                u32 wr0 = wrow[0],   wr1 = wrow[64];
                u32 wz0 = wrow[128], wz1 = wrow[192];
                u32 wn0 = wrow[256], wn1 = wrow[320];
                #pragma unroll
                for (int a = 0; a < 4; a++){
                    u32 hh = h4[a][kk];
                    A_r0[a] = fdot2u(hh, wr0, A_r0[a]);
                    A_r1[a] = fdot2u(hh, wr1, A_r1[a]);
                    A_z0[a] = fdot2u(hh, wz0, A_z0[a]);
                    A_z1[a] = fdot2u(hh, wz1, A_z1[a]);
                    A_h0[a] = fdot2u(hh, wn0, A_h0[a]);
                    A_h1[a] = fdot2u(hh, wn1, A_h1[a]);
                }
            }
        }
        #pragma unroll 2
        for (int k4 = 0; k4 < 8; k4++){
            u32x4 x4[4];
            #pragma unroll
            for (int a = 0; a < 4; a++) x4[a] = *(const u32x4*)&xbuf[w*4+a][k4*4];
            #pragma unroll
            for (int kk = 0; kk < 4; kk++){
                const u32* wrow = &WihT[(k4*4+kk)*384 + lane];
                u32 wr0 = wrow[0],   wr1 = wrow[64];
                u32 wz0 = wrow[128], wz1 = wrow[192];
                u32 wn0 = wrow[256], wn1 = wrow[320];
                #pragma unroll
                for (int a = 0; a < 4; a++){
                    u32 xx = x4[a][kk];
                    A_r0[a] = fdot2u(xx, wr0, A_r0[a]);
                    A_r1[a] = fdot2u(xx, wr1, A_r1[a]);
                    A_z0[a] = fdot2u(xx, wz0, A_z0[a]);
                    A_z1[a] = fdot2u(xx, wz1, A_z1[a]);
                    A_i0[a] = fdot2u(xx, wn0, A_i0[a]);
                    A_i1[a] = fdot2u(xx, wn1, A_i1[a]);
                }
            }
        }
        if (t + 1 < T_STEPS){
            int txn = dir ? (T_STEPS-2-t) : (t+1);
            #pragma unroll
            for (int a = 0; a < 4; a++){
                if (lane < 32) xbuf[w*4+a][lane] = sembu[((size_t)txn*NAG + nb + a)*32 + lane];
            }
        }
        #pragma unroll
        for (int a = 0; a < 4; a++){
            float g0, g1;
            ln128(A_r0[a], A_r1[a], g0, g1);
            float r0 = sigm(g0), r1 = sigm(g1);
            ln128(A_z0[a], A_z1[a], g0, g1);
            float z0 = sigm(g0), z1 = sigm(g1);
            float p0 = A_i0[a] + r0*A_h0[a], p1 = A_i1[a] + r1*A_h1[a];
            ln128(p0, p1, g0, g1);
            float n0 = ftanh(g0), n1 = ftanh(g1);
            float hn0 = (1.f - z0)*n0 + z0*hreg[a][0];
            float hn1 = (1.f - z1)*n1 + z1*hreg[a][1];
            hreg[a][0] = hn0; hreg[a][1] = hn1;
            f16* hp = henc + ((size_t)tx*NAG + nb + a)*128;
            hp[lane] = (f16)hn0; hp[lane+64] = (f16)hn1;
            int sl0 = (2*lane) & 63, sl1 = (2*lane+1) & 63;
            float e0 = __shfl(hn0, sl0), o0 = __shfl(hn1, sl0);
            float e1 = __shfl(hn0, sl1), o1 = __shfl(hn1, sl1);
            hbuf[w*4+a][lane] = pk_h2((lane<32)?e0:o0, (lane<32)?e1:o1);
        }
    }
}

// ---------------- K4: fused post-GRU: seq -> pairwise(factored) -> out head ----------------
__global__ __launch_bounds__(256) void k_post(
    const f16* __restrict__ hf, const f16* __restrict__ hb,
    const void* __restrict__ sw, const void* __restrict__ sb,
    const void* __restrict__ mw, const void* __restrict__ mb,
    const void* __restrict__ ow1, const void* __restrict__ ob1,
    const void* __restrict__ ow2, const void* __restrict__ ob2,
    const void* __restrict__ probe,
    void* __restrict__ outp)
{
    __shared__ u32 swp[64*64];     // [kp][unit]
    __shared__ u32 mwp[32*64];     // [kp][unit]
    __shared__ u32 w1p[64*32];     // [kp][e<32]
    __shared__ u32 xr[4][8][64];   // x=(hf+hb)/2 as f16 pairs
    __shared__ u32 fr[4][8][64];   // full=[seq|ave] pairs
    int F = detect_f32(probe);
    int tid = threadIdx.x;
    for (int i = tid; i < 4096; i += 256){
        int u = i & 63, kp = i >> 6;
        swp[kp*64+u] = ld_pair(sw, u*64 + kp, F);      // sw [64][128]
    }
    for (int i = tid; i < 2048; i += 256){
        int u = i & 63, kp = i >> 6;   // kp < 32
        mwp[kp*64+u] = ld_pair(mw, u*32 + kp, F);      // mw [64][64]
    }
    for (int i = tid; i < 2048; i += 256){
        int e = i & 31, kp = i >> 5;   // kp < 64
        w1p[kp*32+e] = ld_pair(ow1, e*64 + kp, F);     // ow1 [32][128]
    }
    int w = tid >> 6, lane = tid & 63;
    int unit = blockIdx.x*4 + w;        // t*512 + scene
    int t = unit >> 9, sc = unit & 511;
    int base = sc * 8;
    size_t rowbase = (size_t)t*NAG + base;
    const u32* hfu = (const u32*)hf;
    const u32* hbu = (const u32*)hb;
    #pragma unroll
    for (int r = 0; r < 8; r++){
        f32x2 a = unpk_h2(hfu[(rowbase + r)*64 + lane]);
        f32x2 b = unpk_h2(hbu[(rowbase + r)*64 + lane]);
        xr[w][r][lane] = pk_h2(0.5f*(a[0]+b[0]), 0.5f*(a[1]+b[1]));
    }
    __syncthreads();

    float bs = ldin(sb, lane, F);
    float y[8];
    #pragma unroll
    for (int r = 0; r < 8; r++) y[r] = bs;
    for (int kp = 0; kp < 64; kp++){
        u32 wv = swp[kp*64 + lane];
        #pragma unroll
        for (int r = 0; r < 8; r++) y[r] = fdot2u(xr[w][r][kp], wv, y[r]);
    }
    #pragma unroll
    for (int r = 0; r < 8; r++){
        float s = y[r], q = y[r]*y[r]; wred64(s, q);
        float m = s*(1.f/64.f), v = q*(1.f/64.f) - m*m;
        float rs = rsqrtf(fmaxf(v, 0.f) + LN_EPS);
        float sv = lrelu((y[r] - m)*rs);
        float e0 = __shfl(sv, 2*(lane & 31)), e1 = __shfl(sv, 2*(lane & 31) + 1);
        if (lane < 32) fr[w][r][lane] = pk_h2(e0, e1);
    }
    float uu[8];
    #pragma unroll
    for (int r = 0; r < 8; r++) uu[r] = 0.f;
    for (int kp = 0; kp < 32; kp++){
        u32 wv = mwp[kp*64 + lane];
        #pragma unroll
        for (int r = 0; r < 8; r++) uu[r] = fdot2u(fr[w][r][kp], wv, uu[r]);
    }
    float bm = ldin(mb, lane, F);
    #pragma unroll
    for (int i = 0; i < 8; i++){
        float acc = 0.f;
        #pragma unroll
        for (int j = 0; j < 8; j++){
            if (j == i) continue;
            float p = uu[i] - uu[j] + bm;
            float s = p, q = p*p; wred64(s, q);
            float m = s*(1.f/64.f), v = q*(1.f/64.f) - m*m;
            float rs = rsqrtf(fmaxf(v, 0.f) + LN_EPS);
            acc += lrelu((p - m)*rs);
        }
        float av = acc * (1.f/7.f);
        float e0 = __shfl(av, 2*(lane & 31)), e1 = __shfl(av, 2*(lane & 31) + 1);
        if (lane < 32) fr[w][i][32 + lane] = pk_h2(e0, e1);
    }
    int ll = lane & 31;
    float b1v = ldin(ob1, ll, F);
    float o20 = ldin(ow2, ll, F);
    float o21 = ldin(ow2, 32 + ll, F);
    float bo0 = ldin(ob2, 0, F), bo1 = ldin(ob2, 1, F);
    #pragma unroll
    for (int rp = 0; rp < 4; rp++){
        int r = rp*2 + (lane >> 5);
        float h = b1v;
        for (int kp = 0; kp < 64; kp++)
            h = fdot2u(fr[w][r][kp], w1p[kp*32 + ll], h);
        float s = h, q = h*h; wred32(s, q);
        float m = s*(1.f/32.f), v = q*(1.f/32.f) - m*m;
        float rs = rsqrtf(fmaxf(v, 0.f) + LN_EPS);
        float hv = lrelu((h - m)*rs);
        float p0 = hv*o20, p1 = hv*o21;
        wred32(p0, p1);
        if (ll == 0){
            int n = base + r;
            float v0 = ftanh(p0 + bo0), v1 = ftanh(p1 + bo1);
            size_t i0 = (size_t)(n*2)*T_STEPS + t, i1 = (size_t)(n*2+1)*T_STEPS + t;
            if (F){ ((float*)outp)[i0] = v0; ((float*)outp)[i1] = v1; }
            else  { ((u16*)outp)[i0] = f2bf(v0); ((u16*)outp)[i1] = f2bf(v1); }
        }
    }
}

extern "C" void kernel_launch(void* const* d_in, const int* in_sizes, int n_in,
                              void* d_out, int out_size, void* d_ws, size_t ws_size,
                              hipStream_t stream)
{
    const void* cond = d_in[0];
    const void* z    = d_in[1];
    const void* cw1  = d_in[2];
    const void* cb1  = d_in[3];
    const void* cw2  = d_in[4];
    const void* cb2  = d_in[5];
    const void* cbw1 = d_in[6];
    const void* cbb1 = d_in[7];
    const void* cbw2 = d_in[8];
    const void* cbb2 = d_in[9];
    const void* iw1  = d_in[10];
    const void* ib1  = d_in[11];
    const void* iw2  = d_in[12];
    const void* ib2  = d_in[13];
    const void* wih  = d_in[14];
    const void* whh  = d_in[15];
    const void* bih  = d_in[16];
    const void* bhh  = d_in[17];
    const void* wihb = d_in[18];
    const void* whhb = d_in[19];
    const void* bihb = d_in[20];
    const void* bhhb = d_in[21];
    const void* sw   = d_in[22];
    const void* sb   = d_in[23];
    const void* mw   = d_in[24];
    const void* mb   = d_in[25];
    const void* ow1  = d_in[26];
    const void* ob1  = d_in[27];
    const void* ow2  = d_in[28];
    const void* ob2  = d_in[29];
    const void* probe = whh;   // dtype-detection probe buffer

    const size_t sz_disp = (size_t)2*NAG*128*2;           //  2 MB
    const size_t sz_semb = (size_t)T_STEPS*NAG*64*2;      // 15.7 MB
    const size_t sz_henc = (size_t)T_STEPS*NAG*128*2;     // 31.5 MB
    const size_t sz_xg   = (size_t)2*T_STEPS*NAG*384*2;   // 188.7 MB

    char* ws = (char*)d_ws;
    size_t off = 0;
    f16* disp  = (f16*)(ws + off); off += sz_disp;
    f16* semb  = (f16*)(ws + off); off += sz_semb;
    f16* hencF = (f16*)(ws + off); off += sz_henc;
    f16* hencB = (f16*)(ws + off); off += sz_henc;
    f16* xg    = (f16*)(ws + off); off += sz_xg;
    bool fast = (ws_size >= off);

    k_cond<<<dim3(NAG,2), 64, 0, stream>>>(cond, cw1,cb1,cw2,cb2, cbw1,cbb1,cbw2,cbb2, probe, disp);
    k_emb<<<3840, 256, 0, stream>>>(z, iw1,ib1,iw2,ib2, probe, semb);
    if (fast){
        k_xg<<<dim3(3840,2), 256, 0, stream>>>(semb, wih,bih, wihb,bihb, probe, xg);
        k_gru_fast<<<dim3(128,2), 512, 0, stream>>>(xg, disp, whh,bhh, whhb,bhhb, probe, hencF, hencB);
    } else {
        k_gru_fb<<<dim3(128,2), 512, 0, stream>>>(semb, disp, wih,whh,bih,bhh, wihb,whhb,bihb,bhhb, probe, hencF, hencB);
    }
    k_post<<<3840, 256, 0, stream>>>(hencF, hencB, sw,sb, mw,mb, ow1,ob1,ow2,ob2, probe, d_out);
}

// Round 7
// 869.138 us; speedup vs baseline: 2.2434x; 1.3910x over previous
//
#include <hip/hip_runtime.h>
#include <hip/hip_bf16.h>

typedef unsigned int u32;
typedef unsigned short u16;
typedef _Float16 f16;
typedef float f32x2 __attribute__((ext_vector_type(2)));
typedef _Float16 f16x2 __attribute__((ext_vector_type(2)));
typedef u32 u32x4 __attribute__((ext_vector_type(4)));
typedef u32 u32x2v __attribute__((ext_vector_type(2)));
typedef _Float16 f16x8 __attribute__((ext_vector_type(8)));
typedef float f32x4v __attribute__((ext_vector_type(4)));

#define LN_EPS 1e-5f
#define T_STEPS 30
#define NAG 4096

__device__ __forceinline__ float bf2f(u16 v){
    union { u32 u; float f; } c; c.u = ((u32)v) << 16; return c.f;
}
__device__ __forceinline__ u16 f2bf(float f){
    union { float f; u32 u; } c; c.f = f;
    return (u16)((c.u + 0x7FFFu + ((c.u >> 16) & 1u)) >> 16);
}
__device__ __forceinline__ u32 pk_h2(float a, float b){
    f16x2 h; h[0] = (f16)a; h[1] = (f16)b;
    return __builtin_bit_cast(u32, h);
}
__device__ __forceinline__ f32x2 unpk_h2(u32 p){
    f16x2 h = __builtin_bit_cast(f16x2, p);
    f32x2 r; r[0] = (float)h[0]; r[1] = (float)h[1]; return r;
}
__device__ __forceinline__ u32 bfp2h2(u32 p){
    union { u32 u; float f; } a, b;
    a.u = p << 16; b.u = p & 0xFFFF0000u;
    return pk_h2(a.f, b.f);
}
__device__ __forceinline__ float fdot2u(u32 a, u32 b, float c){
    return __builtin_amdgcn_fdot2(__builtin_bit_cast(f16x2, a),
                                  __builtin_bit_cast(f16x2, b), c, false);
}
// dtype probe: fp32 buffers read as u16 have random mantissa halves at even
// positions (~50% decode to |x|>=128); bf16 weight buffers (|w| < 1) never do.
__device__ __forceinline__ int detect_f32(const void* probe){
    const u16* p = (const u16*)probe;
    int bad = 0;
    #pragma unroll
    for (int i = 0; i < 32; i++){
        u32 e = (p[2*i] >> 7) & 0xFF;
        bad += (e >= 0x86) ? 1 : 0;
    }
    return bad > 4;
}
__device__ __forceinline__ float ldin(const void* p, int i, int F){
    float v;
    if (F) v = ((const float*)p)[i];
    else   v = bf2f(((const u16*)p)[i]);
    return v;
}
__device__ __forceinline__ u32 ld_pair(const void* p, int pairIdx, int F){
    if (F){ const float* f = (const float*)p; return pk_h2(f[2*pairIdx], f[2*pairIdx+1]); }
    return bfp2h2(((const u32*)p)[pairIdx]);
}
__device__ __forceinline__ void wred64(float& s, float& q){
    #pragma unroll
    for (int m = 1; m < 64; m <<= 1){ s += __shfl_xor(s, m); q += __shfl_xor(q, m); }
}
__device__ __forceinline__ void wred32(float& s, float& q){
    #pragma unroll
    for (int m = 1; m < 32; m <<= 1){ s += __shfl_xor(s, m); q += __shfl_xor(q, m); }
}
__device__ __forceinline__ float lrelu(float x){ return fmaxf(x, 0.1f * x); }
__device__ __forceinline__ float sigm(float x){ return 1.0f / (1.0f + __expf(-x)); }
__device__ __forceinline__ float ftanh(float x){ return 1.0f - 2.0f / (1.0f + __expf(2.0f * x)); }
__device__ __forceinline__ void ln128(float a0, float a1, float& o0, float& o1){
    float s = a0 + a1, q = a0*a0 + a1*a1;
    wred64(s, q);
    float m = s * (1.f/128.f), v = q * (1.f/128.f) - m*m;
    float rs = rsqrtf(fmaxf(v, 0.f) + LN_EPS);
    o0 = (a0 - m) * rs; o1 = (a1 - m) * rs;
}

// ---------------- K1: cond embeddings (both dirs): [N,2] -> 64 -> 128 ----------------
__global__ __launch_bounds__(64) void k_cond(
    const void* __restrict__ cond,
    const void* __restrict__ w1a, const void* __restrict__ b1a,
    const void* __restrict__ w2a, const void* __restrict__ b2a,
    const void* __restrict__ w1b, const void* __restrict__ b1b,
    const void* __restrict__ w2b, const void* __restrict__ b2b,
    const void* __restrict__ probe,
    f16* __restrict__ disp)
{
    __shared__ float x1s[64];
    int F = detect_f32(probe);
    int n = blockIdx.x, dir = blockIdx.y, lane = threadIdx.x;
    const void* w1 = dir ? w1b : w1a; const void* b1 = dir ? b1b : b1a;
    const void* w2 = dir ? w2b : w2a; const void* b2 = dir ? b2b : b2a;
    float c0 = ldin(cond, n*2, F), c1 = ldin(cond, n*2+1, F);
    float y = ldin(w1, lane*2, F) * c0 + ldin(w1, lane*2+1, F) * c1 + ldin(b1, lane, F);
    float s = y, q = y*y; wred64(s, q);
    float m = s * (1.f/64.f), v = q * (1.f/64.f) - m*m;
    float rs = rsqrtf(fmaxf(v, 0.f) + LN_EPS);
    x1s[lane] = lrelu((y - m) * rs);
    __syncthreads();
    float y0 = ldin(b2, lane, F), y1 = ldin(b2, lane+64, F);
    for (int k = 0; k < 64; k++){
        float xv = x1s[k];
        y0 += ldin(w2, lane*64+k, F) * xv;
        y1 += ldin(w2, (lane+64)*64+k, F) * xv;
    }
    float o0, o1; ln128(y0, y1, o0, o1);
    f16* dp = disp + ((size_t)dir * NAG + n) * 128;
    dp[lane] = (f16)lrelu(o0);
    dp[lane+64] = (f16)lrelu(o1);
}

// ---------------- K2: scene embedding: z[T,N,128] -> 32 -> 64 (packed fdot2) ----------
__global__ __launch_bounds__(256) void k_emb(
    const void* __restrict__ z,
    const void* __restrict__ iw1, const void* __restrict__ ib1,
    const void* __restrict__ iw2, const void* __restrict__ ib2,
    const void* __restrict__ probe,
    f16* __restrict__ semb)
{
    __shared__ u32 w1p[64*32];      // [kp<64][e<32]
    __shared__ u32 w2p[16*64];      // [kp<16][e<64]
    __shared__ u32 zp[4][2][64];    // z rows packed, 2 rows per wave pass
    __shared__ u32 x1p[4][2][16];   // layer-1 outs packed
    int F = detect_f32(probe);
    int tid = threadIdx.x;
    for (int i = tid; i < 2048; i += 256){
        int kp = i >> 5, e = i & 31;
        w1p[kp*32+e] = ld_pair(iw1, e*64 + kp, F);      // iw1 [32][128]
    }
    for (int i = tid; i < 1024; i += 256){
        int kp = i >> 6, e = i & 63;
        w2p[kp*64+e] = ld_pair(iw2, e*16 + kp, F);      // iw2 [64][32]
    }
    __syncthreads();
    int w = tid >> 6, lane = tid & 63;
    int rp = lane >> 5, ll = lane & 31;
    float b1v = ldin(ib1, ll, F);
    float b2v = ldin(ib2, lane, F);
    int rowbase = (blockIdx.x * 4 + w) * 8;
    #pragma unroll 1
    for (int pass = 0; pass < 4; pass++){
        int row = rowbase + pass*2 + rp;                // half-wave rp owns this row
        zp[w][rp][ll]    = ld_pair(z, row*64 + ll, F);
        zp[w][rp][ll+32] = ld_pair(z, row*64 + ll + 32, F);
        float y1 = b1v;
        #pragma unroll 8
        for (int kp = 0; kp < 64; kp++)
            y1 = fdot2u(zp[w][rp][kp], w1p[kp*32+ll], y1);
        float s = y1, q = y1*y1; wred32(s, q);
        float m = s*(1.f/32.f), v = q*(1.f/32.f)-m*m, rs = rsqrtf(fmaxf(v,0.f)+LN_EPS);
        float sv = lrelu((y1-m)*rs);
        float e0 = __shfl(sv, (lane & 32) + 2*(lane & 15));
        float e1 = __shfl(sv, (lane & 32) + 2*(lane & 15) + 1);
        if (ll < 16) x1p[w][rp][ll] = pk_h2(e0, e1);
        #pragma unroll
        for (int r2 = 0; r2 < 2; r2++){
            float y2 = b2v;
            #pragma unroll
            for (int kp = 0; kp < 16; kp++)
                y2 = fdot2u(x1p[w][r2][kp], w2p[kp*64+lane], y2);
            s = y2; q = y2*y2; wred64(s, q);
            m = s*(1.f/64.f); v = q*(1.f/64.f)-m*m; rs = rsqrtf(fmaxf(v,0.f)+LN_EPS);
            semb[(size_t)(rowbase + pass*2 + r2)*64 + lane] = (f16)lrelu((y2-m)*rs);
        }
    }
}

// ---------------- K3: MFMA bidirectional LN-GRU ----------------
// grid (128, 2), 384 thr = 6 waves. Wave w owns M-tiles 4w..4w+3 (16 units each)
// -> gate = w>>1 aligns exactly (r: w0,1; z: w2,3; n: w4,5).
// Verified gfx950 16x16x32 f16 fragment layouts (m89/m91/m120):
//   A[m=lane&15][k=quad*8+j], B[k=quad*8+j][n=lane&15], C col=lane&15 row=quad*4+reg.
// A = W rows (h-K 0..127 from Whh, x-K 128..191 from Wih) resident in 96 VGPRs.
// B = [h; x] per agent in padded LDS rows (b128 frag reads). n-gate keeps separate
// hh / ih accumulators (r gates the hh part only, pre-LN).
__global__ __launch_bounds__(384) void k_gru_mfma(
    const f16* __restrict__ semb, const f16* __restrict__ disp,
    const void* __restrict__ wihA, const void* __restrict__ whhA,
    const void* __restrict__ bihA, const void* __restrict__ bhhA,
    const void* __restrict__ wihB, const void* __restrict__ whhB,
    const void* __restrict__ bihB, const void* __restrict__ bhhB,
    const void* __restrict__ probe,
    f16* __restrict__ hencF, f16* __restrict__ hencB)
{
    __shared__ __align__(16) f16 hbuf[32][136];      // h per agent (pad 8 f16)
    __shared__ __align__(16) f16 xbuf[2][32][72];    // x per agent, double-buffered
    __shared__ __align__(16) f16 rzbuf[2][32][136];  // r,z values [gate][agent][d]
    __shared__ __align__(16) float bias1[384];       // u<256: bih+bhh; u>=256: bih
    __shared__ __align__(16) float bias2[128];       // bhh for n-units
    __shared__ float redS[6][32], redQ[6][32];
    int F = detect_f32(probe);
    int tid = threadIdx.x, dir = blockIdx.y;
    int w = tid >> 6, lane = tid & 63;
    int quad = lane >> 4, l15 = lane & 15;
    int gate = w >> 1;
    const void* wih = dir ? wihB : wihA;  const void* whh = dir ? whhB : whhA;
    const void* bih = dir ? bihB : bihA;  const void* bhh = dir ? bhhB : bhhA;
    f16* henc = dir ? hencB : hencF;

    // ---- A fragments: Af[mt][kt]; lane supplies A[m=l15][k=quad*8+j] ----
    // Dtype branch hoisted; fills fully unrolled with compile-time indices
    // (keeps Af in VGPRs -- the R3/R5 scratch trap).
    f16x8 Af[4][6];
    if (F){
        #pragma unroll
        for (int mt = 0; mt < 4; mt++){
            int u = (w*4+mt)*16 + l15;
            #pragma unroll
            for (int kt = 0; kt < 6; kt++){
                const float* src = (kt < 4)
                    ? ((const float*)whh + (size_t)u*128 + kt*32 + quad*8)
                    : ((const float*)wih + (size_t)u*64 + (kt-4)*32 + quad*8);
                f16x8 v;
                #pragma unroll
                for (int j = 0; j < 8; j++) v[j] = (f16)src[j];
                Af[mt][kt] = v;
            }
        }
    } else {
        #pragma unroll
        for (int mt = 0; mt < 4; mt++){
            int u = (w*4+mt)*16 + l15;
            #pragma unroll
            for (int kt = 0; kt < 6; kt++){
                const u16* src = (kt < 4)
                    ? ((const u16*)whh + (size_t)u*128 + kt*32 + quad*8)
                    : ((const u16*)wih + (size_t)u*64 + (kt-4)*32 + quad*8);
                f16x8 v;
                #pragma unroll
                for (int j = 0; j < 8; j++) v[j] = (f16)bf2f(src[j]);
                Af[mt][kt] = v;
            }
        }
    }
    // biases -> LDS (keeps VGPR pressure down; C-frags init from these per step)
    if (tid < 384){
        float bi = ldin(bih, tid, F), bh = ldin(bhh, tid, F);
        bias1[tid] = (tid < 256) ? (bi + bh) : bi;
        if (tid >= 256) bias2[tid - 256] = bh;
    }

    int nb = blockIdx.x * 32;
    // stage h0 (from disp) and x(t0)
    for (int i = tid; i < 512; i += 384){
        int a = i >> 4, c = i & 15;
        u32x4 v = *(const u32x4*)(disp + ((size_t)dir*NAG + nb + a)*128 + c*8);
        *(u32x4*)&hbuf[a][c*8] = v;
    }
    int tx0 = dir ? (T_STEPS-1) : 0;
    for (int i = tid; i < 256; i += 384){
        int a = i >> 3, c = i & 7;
        u32x4 v = *(const u32x4*)(semb + ((size_t)tx0*NAG + nb + a)*64 + c*8);
        *(u32x4*)&xbuf[0][a][c*8] = v;
    }
    __syncthreads();

    #pragma unroll 1
    for (int t = 0; t < T_STEPS; t++){
        int tx = dir ? (T_STEPS-1-t) : t;
        int cur = t & 1;
        // ---- C init from biases ----
        f32x4v C0[4][2], C1[4][2];
        #pragma unroll
        for (int mt = 0; mt < 4; mt++){
            f32x4v b1f = *(const f32x4v*)&bias1[(w*4+mt)*16 + quad*4];
            if (gate < 2){
                C0[mt][0] = b1f; C0[mt][1] = b1f;          // combined bias
                C1[mt][0] = b1f; C1[mt][1] = b1f;          // unused on this path
            } else {
                f32x4v b2f = *(const f32x4v*)&bias2[((w&1)*4+mt)*16 + quad*4];
                C0[mt][0] = b2f; C0[mt][1] = b2f;          // hh + bhh
                C1[mt][0] = b1f; C1[mt][1] = b1f;          // ih + bih
            }
        }
        // ---- MFMA phase ----
        #pragma unroll
        for (int nt = 0; nt < 2; nt++){
            int ag = nt*16 + l15;
            f16x8 B0 = *(const f16x8*)&hbuf[ag][0*32 + quad*8];
            f16x8 B1 = *(const f16x8*)&hbuf[ag][1*32 + quad*8];
            f16x8 B2 = *(const f16x8*)&hbuf[ag][2*32 + quad*8];
            f16x8 B3 = *(const f16x8*)&hbuf[ag][3*32 + quad*8];
            f16x8 B4 = *(const f16x8*)&xbuf[cur][ag][0*32 + quad*8];
            f16x8 B5 = *(const f16x8*)&xbuf[cur][ag][1*32 + quad*8];
            if (gate < 2){
                #pragma unroll
                for (int mt = 0; mt < 4; mt++){
                    f32x4v c = C0[mt][nt];
                    c = __builtin_amdgcn_mfma_f32_16x16x32_f16(Af[mt][0], B0, c, 0, 0, 0);
                    c = __builtin_amdgcn_mfma_f32_16x16x32_f16(Af[mt][1], B1, c, 0, 0, 0);
                    c = __builtin_amdgcn_mfma_f32_16x16x32_f16(Af[mt][2], B2, c, 0, 0, 0);
                    c = __builtin_amdgcn_mfma_f32_16x16x32_f16(Af[mt][3], B3, c, 0, 0, 0);
                    c = __builtin_amdgcn_mfma_f32_16x16x32_f16(Af[mt][4], B4, c, 0, 0, 0);
                    c = __builtin_amdgcn_mfma_f32_16x16x32_f16(Af[mt][5], B5, c, 0, 0, 0);
                    C0[mt][nt] = c;
                }
            } else {
                #pragma unroll
                for (int mt = 0; mt < 4; mt++){
                    f32x4v c = C0[mt][nt];
                    c = __builtin_amdgcn_mfma_f32_16x16x32_f16(Af[mt][0], B0, c, 0, 0, 0);
                    c = __builtin_amdgcn_mfma_f32_16x16x32_f16(Af[mt][1], B1, c, 0, 0, 0);
                    c = __builtin_amdgcn_mfma_f32_16x16x32_f16(Af[mt][2], B2, c, 0, 0, 0);
                    c = __builtin_amdgcn_mfma_f32_16x16x32_f16(Af[mt][3], B3, c, 0, 0, 0);
                    C0[mt][nt] = c;
                    f32x4v d = C1[mt][nt];
                    d = __builtin_amdgcn_mfma_f32_16x16x32_f16(Af[mt][4], B4, d, 0, 0, 0);
                    d = __builtin_amdgcn_mfma_f32_16x16x32_f16(Af[mt][5], B5, d, 0, 0, 0);
                    C1[mt][nt] = d;
                }
            }
        }
        // ---- phase1 tail: r/z LN partials; n-waves stage next x ----
        if (gate < 2){
            #pragma unroll
            for (int nt = 0; nt < 2; nt++){
                float s = 0.f, q = 0.f;
                #pragma unroll
                for (int mt = 0; mt < 4; mt++)
                    #pragma unroll
                    for (int r = 0; r < 4; r++){
                        float v = C0[mt][nt][r];
                        s += v; q += v*v;
                    }
                s += __shfl_xor(s, 16); q += __shfl_xor(q, 16);
                s += __shfl_xor(s, 32); q += __shfl_xor(q, 32);
                if (lane < 16){ redS[w][nt*16 + l15] = s; redQ[w][nt*16 + l15] = q; }
            }
        } else {
            if (t + 1 < T_STEPS){
                int txn = dir ? (T_STEPS-2-t) : (t+1);
                int i0 = (w-4)*64 + lane;                  // [0,128)
                #pragma unroll
                for (int rep = 0; rep < 2; rep++){
                    int i = i0 + rep*128;
                    int a = i >> 3, c = i & 7;
                    u32x4 v = *(const u32x4*)(semb + ((size_t)txn*NAG + nb + a)*64 + c*8);
                    *(u32x4*)&xbuf[cur^1][a][c*8] = v;
                }
            }
        }
        __syncthreads();                                   // bar1
        // ---- phase2: r/z finalize LN + sigmoid -> rzbuf ----
        if (gate < 2){
            #pragma unroll
            for (int nt = 0; nt < 2; nt++){
                int ag = nt*16 + l15;
                float s = redS[w][ag] + redS[w^1][ag];
                float q = redQ[w][ag] + redQ[w^1][ag];
                float m = s*(1.f/128.f), vv = q*(1.f/128.f) - m*m;
                float rs = rsqrtf(fmaxf(vv, 0.f) + LN_EPS);
                #pragma unroll
                for (int mt = 0; mt < 4; mt++){
                    float g0 = sigm((C0[mt][nt][0] - m)*rs);
                    float g1 = sigm((C0[mt][nt][1] - m)*rs);
                    float g2 = sigm((C0[mt][nt][2] - m)*rs);
                    float g3 = sigm((C0[mt][nt][3] - m)*rs);
                    int dg = ((w&1)*4 + mt)*16 + quad*4;
                    u32x2v p; p.x = pk_h2(g0, g1); p.y = pk_h2(g2, g3);
                    *(u32x2v*)&rzbuf[gate][ag][dg] = p;
                }
            }
        }
        __syncthreads();                                   // bar2
        // ---- phase3: n-pre = ih + r * hh ; LN partials ----
        if (gate == 2){
            #pragma unroll
            for (int nt = 0; nt < 2; nt++){
                int ag = nt*16 + l15;
                float s = 0.f, q = 0.f;
                #pragma unroll
                for (int mt = 0; mt < 4; mt++){
                    int dg = ((w&1)*4 + mt)*16 + quad*4;
                    u32x2v rp = *(const u32x2v*)&rzbuf[0][ag][dg];
                    f32x2 ra = unpk_h2(rp.x), rb = unpk_h2(rp.y);
                    float p0 = C1[mt][nt][0] + ra[0]*C0[mt][nt][0];
                    float p1 = C1[mt][nt][1] + ra[1]*C0[mt][nt][1];
                    float p2 = C1[mt][nt][2] + rb[0]*C0[mt][nt][2];
                    float p3 = C1[mt][nt][3] + rb[1]*C0[mt][nt][3];
                    C0[mt][nt][0] = p0; C0[mt][nt][1] = p1;
                    C0[mt][nt][2] = p2; C0[mt][nt][3] = p3;
                    s += p0 + p1 + p2 + p3;
                    q += p0*p0 + p1*p1 + p2*p2 + p3*p3;
                }
                s += __shfl_xor(s, 16); q += __shfl_xor(q, 16);
                s += __shfl_xor(s, 32); q += __shfl_xor(q, 32);
                if (lane < 16){ redS[w][ag] = s; redQ[w][ag] = q; }
            }
        }
        __syncthreads();                                   // bar3
        // ---- phase4: n finalize, h update, write back ----
        if (gate == 2){
            #pragma unroll
            for (int nt = 0; nt < 2; nt++){
                int ag = nt*16 + l15;
                float s = redS[4][ag] + redS[5][ag];
                float q = redQ[4][ag] + redQ[5][ag];
                float m = s*(1.f/128.f), vv = q*(1.f/128.f) - m*m;
                float rs = rsqrtf(fmaxf(vv, 0.f) + LN_EPS);
                #pragma unroll
                for (int mt = 0; mt < 4; mt++){
                    int dg = ((w&1)*4 + mt)*16 + quad*4;
                    float n0 = ftanh((C0[mt][nt][0] - m)*rs);
                    float n1 = ftanh((C0[mt][nt][1] - m)*rs);
                    float n2 = ftanh((C0[mt][nt][2] - m)*rs);
                    float n3 = ftanh((C0[mt][nt][3] - m)*rs);
                    u32x2v zp = *(const u32x2v*)&rzbuf[1][ag][dg];
                    f32x2 za = unpk_h2(zp.x), zb = unpk_h2(zp.y);
                    u32x2v hp = *(const u32x2v*)&hbuf[ag][dg];
                    f32x2 ha = unpk_h2(hp.x), hb2 = unpk_h2(hp.y);
                    float h0 = (1.f - za[0])*n0 + za[0]*ha[0];
                    float h1 = (1.f - za[1])*n1 + za[1]*ha[1];
                    float h2 = (1.f - zb[0])*n2 + zb[0]*hb2[0];
                    float h3 = (1.f - zb[1])*n3 + zb[1]*hb2[1];
                    u32x2v o; o.x = pk_h2(h0, h1); o.y = pk_h2(h2, h3);
                    *(u32x2v*)&hbuf[ag][dg] = o;
                    *(u32x2v*)(henc + ((size_t)tx*NAG + nb + ag)*128 + dg) = o;
                }
            }
        }
        __syncthreads();                                   // bar4
    }
}

// ---------------- K4: fused post-GRU: seq -> pairwise(factored) -> out head ----------------
__global__ __launch_bounds__(256) void k_post(
    const f16* __restrict__ hf, const f16* __restrict__ hb,
    const void* __restrict__ sw, const void* __restrict__ sb,
    const void* __restrict__ mw, const void* __restrict__ mb,
    const void* __restrict__ ow1, const void* __restrict__ ob1,
    const void* __restrict__ ow2, const void* __restrict__ ob2,
    const void* __restrict__ probe,
    void* __restrict__ outp)
{
    __shared__ u32 swp[64*64];     // [kp][unit]
    __shared__ u32 mwp[32*64];     // [kp][unit]
    __shared__ u32 w1p[64*32];     // [kp][e<32]
    __shared__ u32 xr[4][8][64];   // x=(hf+hb)/2 as f16 pairs
    __shared__ u32 fr[4][8][64];   // full=[seq|ave] pairs
    int F = detect_f32(probe);
    int tid = threadIdx.x;
    for (int i = tid; i < 4096; i += 256){
        int u = i & 63, kp = i >> 6;
        swp[kp*64+u] = ld_pair(sw, u*64 + kp, F);      // sw [64][128]
    }
    for (int i = tid; i < 2048; i += 256){
        int u = i & 63, kp = i >> 6;   // kp < 32
        mwp[kp*64+u] = ld_pair(mw, u*32 + kp, F);      // mw [64][64]
    }
    for (int i = tid; i < 2048; i += 256){
        int e = i & 31, kp = i >> 5;   // kp < 64
        w1p[kp*32+e] = ld_pair(ow1, e*64 + kp, F);     // ow1 [32][128]
    }
    int w = tid >> 6, lane = tid & 63;
    int unit = blockIdx.x*4 + w;        // t*512 + scene
    int t = unit >> 9, sc = unit & 511;
    int base = sc * 8;
    size_t rowbase = (size_t)t*NAG + base;
    const u32* hfu = (const u32*)hf;
    const u32* hbu = (const u32*)hb;
    #pragma unroll
    for (int r = 0; r < 8; r++){
        f32x2 a = unpk_h2(hfu[(rowbase + r)*64 + lane]);
        f32x2 b = unpk_h2(hbu[(rowbase + r)*64 + lane]);
        xr[w][r][lane] = pk_h2(0.5f*(a[0]+b[0]), 0.5f*(a[1]+b[1]));
    }
    __syncthreads();

    float bs = ldin(sb, lane, F);
    float y[8];
    #pragma unroll
    for (int r = 0; r < 8; r++) y[r] = bs;
    for (int kp = 0; kp < 64; kp++){
        u32 wv = swp[kp*64 + lane];
        #pragma unroll
        for (int r = 0; r < 8; r++) y[r] = fdot2u(xr[w][r][kp], wv, y[r]);
    }
    #pragma unroll
    for (int r = 0; r < 8; r++){
        float s = y[r], q = y[r]*y[r]; wred64(s, q);
        float m = s*(1.f/64.f), v = q*(1.f/64.f) - m*m;
        float rs = rsqrtf(fmaxf(v, 0.f) + LN_EPS);
        float sv = lrelu((y[r] - m)*rs);
        float e0 = __shfl(sv, 2*(lane & 31)), e1 = __shfl(sv, 2*(lane & 31) + 1);
        if (lane < 32) fr[w][r][lane] = pk_h2(e0, e1);
    }
    float uu[8];
    #pragma unroll
    for (int r = 0; r < 8; r++) uu[r] = 0.f;
    for (int kp = 0; kp < 32; kp++){
        u32 wv = mwp[kp*64 + lane];
        #pragma unroll
        for (int r = 0; r < 8; r++) uu[r] = fdot2u(fr[w][r][kp], wv, uu[r]);
    }
    float bm = ldin(mb, lane, F);
    #pragma unroll
    for (int i = 0; i < 8; i++){
        float acc = 0.f;
        #pragma unroll
        for (int j = 0; j < 8; j++){
            if (j == i) continue;
            float p = uu[i] - uu[j] + bm;
            float s = p, q = p*p; wred64(s, q);
            float m = s*(1.f/64.f), v = q*(1.f/64.f) - m*m;
            float rs = rsqrtf(fmaxf(v, 0.f) + LN_EPS);
            acc += lrelu((p - m)*rs);
        }
        float av = acc * (1.f/7.f);
        float e0 = __shfl(av, 2*(lane & 31)), e1 = __shfl(av, 2*(lane & 31) + 1);
        if (lane < 32) fr[w][i][32 + lane] = pk_h2(e0, e1);
    }
    int ll = lane & 31;
    float b1v = ldin(ob1, ll, F);
    float o20 = ldin(ow2, ll, F);
    float o21 = ldin(ow2, 32 + ll, F);
    float bo0 = ldin(ob2, 0, F), bo1 = ldin(ob2, 1, F);
    #pragma unroll
    for (int rp = 0; rp < 4; rp++){
        int r = rp*2 + (lane >> 5);
        float h = b1v;
        for (int kp = 0; kp < 64; kp++)
            h = fdot2u(fr[w][r][kp], w1p[kp*32 + ll], h);
        float s = h, q = h*h; wred32(s, q);
        float m = s*(1.f/32.f), v = q*(1.f/32.f) - m*m;
        float rs = rsqrtf(fmaxf(v, 0.f) + LN_EPS);
        float hv = lrelu((h - m)*rs);
        float p0 = hv*o20, p1 = hv*o21;
        wred32(p0, p1);
        if (ll == 0){
            int n = base + r;
            float v0 = ftanh(p0 + bo0), v1 = ftanh(p1 + bo1);
            size_t i0 = (size_t)(n*2)*T_STEPS + t, i1 = (size_t)(n*2+1)*T_STEPS + t;
            if (F){ ((float*)outp)[i0] = v0; ((float*)outp)[i1] = v1; }
            else  { ((u16*)outp)[i0] = f2bf(v0); ((u16*)outp)[i1] = f2bf(v1); }
        }
    }
}

extern "C" void kernel_launch(void* const* d_in, const int* in_sizes, int n_in,
                              void* d_out, int out_size, void* d_ws, size_t ws_size,
                              hipStream_t stream)
{
    const void* cond = d_in[0];
    const void* z    = d_in[1];
    const void* cw1  = d_in[2];
    const void* cb1  = d_in[3];
    const void* cw2  = d_in[4];
    const void* cb2  = d_in[5];
    const void* cbw1 = d_in[6];
    const void* cbb1 = d_in[7];
    const void* cbw2 = d_in[8];
    const void* cbb2 = d_in[9];
    const void* iw1  = d_in[10];
    const void* ib1  = d_in[11];
    const void* iw2  = d_in[12];
    const void* ib2  = d_in[13];
    const void* wih  = d_in[14];
    const void* whh  = d_in[15];
    const void* bih  = d_in[16];
    const void* bhh  = d_in[17];
    const void* wihb = d_in[18];
    const void* whhb = d_in[19];
    const void* bihb = d_in[20];
    const void* bhhb = d_in[21];
    const void* sw   = d_in[22];
    const void* sb   = d_in[23];
    const void* mw   = d_in[24];
    const void* mb   = d_in[25];
    const void* ow1  = d_in[26];
    const void* ob1  = d_in[27];
    const void* ow2  = d_in[28];
    const void* ob2  = d_in[29];
    const void* probe = whh;   // dtype-detection probe buffer

    char* ws = (char*)d_ws;
    size_t off = 0;
    f16* disp  = (f16*)(ws + off); off += (size_t)2*NAG*128*2;          //  2 MB
    f16* semb  = (f16*)(ws + off); off += (size_t)T_STEPS*NAG*64*2;     // 15.7 MB
    f16* hencF = (f16*)(ws + off); off += (size_t)T_STEPS*NAG*128*2;    // 31.5 MB
    f16* hencB = (f16*)(ws + off); off += (size_t)T_STEPS*NAG*128*2;    // 31.5 MB

    k_cond<<<dim3(NAG,2), 64, 0, stream>>>(cond, cw1,cb1,cw2,cb2, cbw1,cbb1,cbw2,cbb2, probe, disp);
    k_emb<<<3840, 256, 0, stream>>>(z, iw1,ib1,iw2,ib2, probe, semb);
    k_gru_mfma<<<dim3(NAG/32,2), 384, 0, stream>>>(semb, disp, wih,whh,bih,bhh, wihb,whhb,bihb,bhhb, probe, hencF, hencB);
    k_post<<<3840, 256, 0, stream>>>(hencF, hencB, sw,sb, mw,mb, ow1,ob1,ow2,ob2, probe, d_out);
}